// Round 6
// baseline (304.145 us; speedup 1.0000x reference)
//
#include <hip/hip_runtime.h>

// SparseMaxPool — R5 (first perf round; R4 passed with absmax 0).
// fp32 in, fp32 out. dur_us 266 includes the harness's 163 us poison fill;
// pool_map itself was ~90 us (~2.9 TB/s) vs the 6.6 TB/s the fill proves.
// Fix: per-block precomputed u16 byte-offset table idx[4096] (tile structure
// is identical for all 16384 tiles) -> emit loop is 1x8B idx read + 4
// unconditional LDS loads (invalid positions hit a shared zero slot =
// broadcast) + 1 float4 store. No branches, no barriers in the main loop
// (vals is wave-private, idx read-only). Grid-stride amortizes idx build.
// LDS 25.9 KB -> 6 blocks/CU (24 waves) via __launch_bounds__(256,6).

typedef unsigned short u16;
typedef unsigned int   u32;

// 31 pool stages: output length and offset of each stage's values in the
// compact per-row vals[] (vals[0..63] = original x). Stages 15 and 23 are
// k=3,s=2; the rest k=2,s=1.  (Verified: absmax 0.0 in R4.)
__device__ __constant__ int SPEC_LEN[31] = {
  63,62,61,60,59,58,57,56,55,54,53,52,51,50,49,
  24,23,22,21,20,19,18,17,
  8,7,6,5,4,3,2,1};
__device__ __constant__ int SPEC_BASE[31] = {
  64,127,189,250,310,369,427,484,540,595,649,702,754,805,855,
  904,928,951,973,994,1014,1033,1051,
  1068,1076,1083,1089,1094,1098,1101,1103};

// Diff table: for d = c - r in [0,63], entry = base | (shift<<16) | 1<<24.
// Valid iff entry != 0 && (r & ((1<<shift)-1)) == 0.
#define E(base, sh) ((base) | ((sh) << 16) | (1 << 24))
__device__ __constant__ int DTAB[64] = {
  E(0,0),   E(64,0),  E(127,0), E(189,0), E(250,0), E(310,0), E(369,0), E(427,0),
  E(484,0), E(540,0), E(595,0), E(649,0), E(702,0), E(754,0), E(805,0), E(855,0),
  0,        E(904,1), 0,        E(928,1), 0,        E(951,1), 0,        E(973,1),
  0,        E(994,1), 0,        E(1014,1),0,        E(1033,1),0,        E(1051,1),
  0, 0, 0,  E(1068,2),0, 0, 0,  E(1076,2),0, 0, 0,  E(1083,2),0, 0, 0,  E(1089,2),
  0, 0, 0,  E(1094,2),0, 0, 0,  E(1098,2),0, 0, 0,  E(1101,2),0, 0, 0,  E(1103,2)
};
#undef E

__global__ void __launch_bounds__(256, 6)
pool_map_kernel(const float* __restrict__ x, float* __restrict__ out, int ngroups) {
  // Per-wave value array: 1104 pooled values + 8-float zero slot (byte 4416).
  __shared__ float vals[4][1112];
  // Per-block tile-structure table: byte offset into a wave's vals[] row
  // for each of the 4096 tile positions (4416 = zero slot). Same for all tiles.
  __shared__ u16 idx[4096];

  const int tid  = threadIdx.x;
  const int w    = tid >> 6;
  const int lane = tid & 63;

  // Build idx once per block (16 entries/thread).
#pragma unroll
  for (int k = 0; k < 16; ++k) {
    const int f = tid + k * 256;
    const int r = f >> 6, c = f & 63, d = c - r;
    u16 off = 4416;                         // zero slot
    if (d >= 0) {
      const int e  = DTAB[d];
      const int sh = (e >> 16) & 0xFF;
      if (e != 0 && ((r & ((1 << sh) - 1)) == 0))
        off = (u16)(((e & 0xFFFF) + (r >> sh)) * 4);
    }
    idx[f] = off;
  }
  if (lane < 8) vals[w][1104 + lane] = 0.f; // zero slot, written once
  __syncthreads();                          // idx + zero slots ready

  const char* valsw = (const char*)&vals[w][0];

  for (int grp = blockIdx.x; grp < ngroups; grp += gridDim.x) {
    const int row = grp * 4 + w;            // (b*D + d) row; wave-private tile
    float cur = x[(size_t)row * 64 + lane];
    vals[w][lane] = cur;

    // 31-stage pool chain (wave-synchronous shuffles; verified in R4).
#pragma unroll
    for (int m = 0; m < 31; ++m) {
      if (m == 15 || m == 23) {             // k=3, s=2
        float a = __shfl(cur, 2 * lane);
        float b = __shfl(cur, 2 * lane + 1);
        float c = __shfl(cur, 2 * lane + 2);
        cur = fmaxf(fmaxf(a, b), c);
      } else {                              // k=2, s=1
        cur = fmaxf(cur, __shfl_down(cur, 1));
      }
      if (lane < SPEC_LEN[m]) vals[w][SPEC_BASE[m] + lane] = cur;
    }

    // Emit 64x64 fp32 tile: 16 x (8B idx read + 4 LDS loads + float4 store).
    // Invalid positions read the zero slot (same address -> LDS broadcast).
    float* orow = out + (size_t)row * 4096;
#pragma unroll 4
    for (int it = 0; it < 16; ++it) {
      const int f = it * 256 + lane * 4;
      const uint2 p = *(const uint2*)&idx[f];
      float4 o;
      o.x = *(const float*)(valsw + (p.x & 0xFFFFu));
      o.y = *(const float*)(valsw + (p.x >> 16));
      o.z = *(const float*)(valsw + (p.y & 0xFFFFu));
      o.w = *(const float*)(valsw + (p.y >> 16));
      *(float4*)(orow + f) = o;
    }
    // No barrier: vals[w] is wave-private (in-wave LDS ordering suffices),
    // idx is read-only after the initial barrier.
  }
}

__device__ __forceinline__ float mask_val(int r, int c) {
  const int d = c - r;
  if (d < 0) return 0.f;
  const int e  = DTAB[d];
  const int sh = (e >> 16) & 0xFF;
  return (e != 0 && ((r & ((1 << sh) - 1)) == 0)) ? 1.f : 0.f;
}

__global__ void __launch_bounds__(256)
mask_kernel(float* __restrict__ out, int nvec) {
  const int i = blockIdx.x * 256 + threadIdx.x;  // one float4 per thread
  if (i >= nvec) return;
  const int f  = (i * 4) & 4095;
  const int r  = f >> 6;
  const int c0 = f & 63;
  float4 o;
  o.x = mask_val(r, c0);
  o.y = mask_val(r, c0 + 1);
  o.z = mask_val(r, c0 + 2);
  o.w = mask_val(r, c0 + 3);
  *(float4*)(out + (size_t)i * 4) = o;
}

extern "C" void kernel_launch(void* const* d_in, const int* in_sizes, int n_in,
                              void* d_out, int out_size, void* d_ws, size_t ws_size,
                              hipStream_t stream) {
  const float* x = (const float*)d_in[0];        // fp32 input
  float* out = (float*)d_out;                    // fp32 output

  const int nx      = in_sizes[0];               // B*D*64 = 1048576
  const int nrows   = nx / 64;                   // B*D    = 16384
  const int ngroups = nrows / 4;                 // 4096 row-groups of 4
  const int B       = out_size / 4096 - nrows;   // 32 mask copies

  // 2048 blocks x 2 groups: enough to fill 6 blocks/CU x 256 CUs, grid-stride
  // amortizes the idx build and keeps waves resident.
  pool_map_kernel<<<dim3(2048), 256, 0, stream>>>(x, out, ngroups);

  float* omask = out + (size_t)nrows * 4096;
  const int nvec = (B * 4096) / 4;
  mask_kernel<<<dim3((nvec + 255) / 256), 256, 0, stream>>>(omask, nvec);
}

// Round 7
// 274.041 us; speedup vs baseline: 1.1099x; 1.1099x over previous
//
#include <hip/hip_runtime.h>

// SparseMaxPool — R6. R5 (+40 us vs R4) post-mortem: (1) 2048 grid-stride
// blocks vs 1536 resident (launch_bounds 6) -> 1.33 scheduling rounds;
// (2) unroll-4 emit interleaved idx->val->store dependency chains, so store
// issue serialized on lgkmcnt. The harness fill hits 6.6 TB/s at ~10%
// occupancy -> streaming writes need back-to-back stores, not occupancy.
// Fix: 4096 independent blocks (one tile-group each, dynamic drain) + emit
// restructured as gather-batches (8x idx, 32x val reads, then 8 stores
// back-to-back), x2. Keep the cheap idx-table addressing from R5.

typedef unsigned short u16;
typedef unsigned int   u32;

// 31 pool stages (verified absmax 0.0 in R4/R5): output length and offset of
// each stage's values in the compact per-row vals[] (vals[0..63] = x).
// Stages 15 and 23 are k=3,s=2; the rest k=2,s=1.
__device__ __constant__ int SPEC_LEN[31] = {
  63,62,61,60,59,58,57,56,55,54,53,52,51,50,49,
  24,23,22,21,20,19,18,17,
  8,7,6,5,4,3,2,1};
__device__ __constant__ int SPEC_BASE[31] = {
  64,127,189,250,310,369,427,484,540,595,649,702,754,805,855,
  904,928,951,973,994,1014,1033,1051,
  1068,1076,1083,1089,1094,1098,1101,1103};

// Diff table: for d = c - r in [0,63], entry = base | (shift<<16) | 1<<24.
// Valid iff entry != 0 && (r & ((1<<shift)-1)) == 0.
#define E(base, sh) ((base) | ((sh) << 16) | (1 << 24))
__device__ __constant__ int DTAB[64] = {
  E(0,0),   E(64,0),  E(127,0), E(189,0), E(250,0), E(310,0), E(369,0), E(427,0),
  E(484,0), E(540,0), E(595,0), E(649,0), E(702,0), E(754,0), E(805,0), E(855,0),
  0,        E(904,1), 0,        E(928,1), 0,        E(951,1), 0,        E(973,1),
  0,        E(994,1), 0,        E(1014,1),0,        E(1033,1),0,        E(1051,1),
  0, 0, 0,  E(1068,2),0, 0, 0,  E(1076,2),0, 0, 0,  E(1083,2),0, 0, 0,  E(1089,2),
  0, 0, 0,  E(1094,2),0, 0, 0,  E(1098,2),0, 0, 0,  E(1101,2),0, 0, 0,  E(1103,2)
};
#undef E

__global__ void __launch_bounds__(256)
pool_map_kernel(const float* __restrict__ x, float* __restrict__ out) {
  // Per-wave value array: 1104 pooled values + 8-float zero slot (byte 4416).
  __shared__ float vals[4][1112];
  // Tile-structure table: byte offset into a wave's vals[] for each of the
  // 4096 tile positions (4416 = zero slot). Identical for every tile.
  __shared__ u16 idx[4096];

  const int tid  = threadIdx.x;
  const int w    = tid >> 6;
  const int lane = tid & 63;

  // Build idx (16 entries/thread).
#pragma unroll
  for (int k = 0; k < 16; ++k) {
    const int f = tid + k * 256;
    const int r = f >> 6, c = f & 63, d = c - r;
    u16 off = 4416;                         // zero slot
    if (d >= 0) {
      const int e  = DTAB[d];
      const int sh = (e >> 16) & 0xFF;
      if (e != 0 && ((r & ((1 << sh) - 1)) == 0))
        off = (u16)(((e & 0xFFFF) + (r >> sh)) * 4);
    }
    idx[f] = off;
  }
  if (lane < 8) vals[w][1104 + lane] = 0.f; // zero slot
  __syncthreads();                          // idx + zero slots ready

  const int row = blockIdx.x * 4 + w;       // (b*D + d) row; wave-private tile
  float cur = x[(size_t)row * 64 + lane];
  vals[w][lane] = cur;

  // 31-stage pool chain (wave-synchronous shuffles; verified).
#pragma unroll
  for (int m = 0; m < 31; ++m) {
    if (m == 15 || m == 23) {               // k=3, s=2
      float a = __shfl(cur, 2 * lane);
      float b = __shfl(cur, 2 * lane + 1);
      float c = __shfl(cur, 2 * lane + 2);
      cur = fmaxf(fmaxf(a, b), c);
    } else {                                // k=2, s=1
      cur = fmaxf(cur, __shfl_down(cur, 1));
    }
    if (lane < SPEC_LEN[m]) vals[w][SPEC_BASE[m] + lane] = cur;
  }
  // No extra barrier: vals[w] is wave-private; in-wave LDS ordering suffices.

  // Emit the 64x64 fp32 tile in two gather-batches: load 8 idx pairs, do 32
  // LDS value reads (invalid -> shared zero slot = broadcast), THEN issue 8
  // float4 stores back-to-back (fill-kernel style, no lgkmcnt between them).
  const char* valsw = (const char*)&vals[w][0];
  float* orow = out + (size_t)row * 4096;
#pragma unroll
  for (int half = 0; half < 2; ++half) {
    const int fbase = half * 2048 + lane * 4;
    uint2 p[8];
#pragma unroll
    for (int it = 0; it < 8; ++it)
      p[it] = *(const uint2*)&idx[fbase + it * 256];
    float4 o[8];
#pragma unroll
    for (int it = 0; it < 8; ++it) {
      o[it].x = *(const float*)(valsw + (p[it].x & 0xFFFFu));
      o[it].y = *(const float*)(valsw + (p[it].x >> 16));
      o[it].z = *(const float*)(valsw + (p[it].y & 0xFFFFu));
      o[it].w = *(const float*)(valsw + (p[it].y >> 16));
    }
#pragma unroll
    for (int it = 0; it < 8; ++it)
      *(float4*)(orow + fbase + it * 256) = o[it];
  }
}

__device__ __forceinline__ float mask_val(int r, int c) {
  const int d = c - r;
  if (d < 0) return 0.f;
  const int e  = DTAB[d];
  const int sh = (e >> 16) & 0xFF;
  return (e != 0 && ((r & ((1 << sh) - 1)) == 0)) ? 1.f : 0.f;
}

__global__ void __launch_bounds__(256)
mask_kernel(float* __restrict__ out, int nvec) {
  const int i = blockIdx.x * 256 + threadIdx.x;  // one float4 per thread
  if (i >= nvec) return;
  const int f  = (i * 4) & 4095;
  const int r  = f >> 6;
  const int c0 = f & 63;
  float4 o;
  o.x = mask_val(r, c0);
  o.y = mask_val(r, c0 + 1);
  o.z = mask_val(r, c0 + 2);
  o.w = mask_val(r, c0 + 3);
  *(float4*)(out + (size_t)i * 4) = o;
}

extern "C" void kernel_launch(void* const* d_in, const int* in_sizes, int n_in,
                              void* d_out, int out_size, void* d_ws, size_t ws_size,
                              hipStream_t stream) {
  const float* x = (const float*)d_in[0];        // fp32 input
  float* out = (float*)d_out;                    // fp32 output

  const int nx    = in_sizes[0];                 // B*D*64 = 1048576
  const int nrows = nx / 64;                     // B*D    = 16384
  const int B     = out_size / 4096 - nrows;     // 32 mask copies

  // One 4-row group per block, 4096 independent blocks (dynamic drain; no
  // grid-stride co-residency imbalance).
  pool_map_kernel<<<dim3(nrows / 4), 256, 0, stream>>>(x, out);

  float* omask = out + (size_t)nrows * 4096;
  const int nvec = (B * 4096) / 4;
  mask_kernel<<<dim3((nvec + 255) / 256), 256, 0, stream>>>(omask, nvec);
}

// Round 8
// 263.754 us; speedup vs baseline: 1.1531x; 1.0390x over previous
//
#include <hip/hip_runtime.h>

// SparseMaxPool — R7. R4≈R6 (~100 us for pool_map) => emit style irrelevant;
// bottleneck = LDS gather pressure (64 conflicted b32/tile + idx reads) and
// gather->store chains. New structure: persistent 16 KB LDS tile per wave,
// zeroed ONCE; pool chain scatters its 1104 values directly to (i,j) LDS
// positions (conflict-free strides); zeros persist across tiles (valid set is
// fixed). Emit = 16x ds_read_b128 + 16x dwordx4 stores, no indirection.
// Mask tiles are map tiles with all-ones input (maxpool(1)=1) -> ONE kernel.
// 64-thread blocks, (ntiles/8)=2056 blocks -> 10 resident/CU capacity, one
// scheduling round, 8 tiles each, next-x prefetched during emit.

// Per-stage constants (constexpr -> folded to immediates in the unrolled
// loop; ds_write offsets become imm fields). Verified geometry (absmax 0.0
// in R4-R6): stages 0-14 st=1 off=1..15 len=63..49; 15-22 st=2 off=17,19..31
// len=24..17; 23-30 st=4 off=35,39..63 len=8..1. k=3,s=2 at m=15,23.
constexpr int S_LEN[31] = {
  63,62,61,60,59,58,57,56,55,54,53,52,51,50,49,
  24,23,22,21,20,19,18,17,
  8,7,6,5,4,3,2,1};
constexpr int S_ST[31] = {
  1,1,1,1,1,1,1,1,1,1,1,1,1,1,1,
  2,2,2,2,2,2,2,2,
  4,4,4,4,4,4,4,4};
constexpr int S_OFF[31] = {
  1,2,3,4,5,6,7,8,9,10,11,12,13,14,15,
  17,19,21,23,25,27,29,31,
  35,39,43,47,51,55,59,63};

__global__ void __launch_bounds__(64)
sparse_pool_kernel(const float* __restrict__ x, float* __restrict__ out,
                   int nrows, int ntiles) {
  __shared__ float tile[4096];            // 16 KB: one 64x64 fp32 tile
  const int lane = threadIdx.x;

  // Zero the tile ONCE. Valid positions are overwritten every tile; the
  // zero background persists (the valid-position set is tile-invariant).
  const float4 z = make_float4(0.f, 0.f, 0.f, 0.f);
#pragma unroll
  for (int i = 0; i < 16; ++i)
    ((float4*)tile)[i * 64 + lane] = z;

  int t = blockIdx.x;
  float curx = 0.f;
  if (t < ntiles) curx = (t < nrows) ? x[(size_t)t * 64 + lane] : 1.0f;

  for (; t < ntiles; t += gridDim.x) {
    // Diagonal (st=1 pattern: bank = lane%32, 2-way across the wave = free).
    tile[lane * 65] = curx;

    // 31-stage pool chain (verified shuffles), scattering each stage's
    // output straight to its tile positions: addr = lane*st*65 + off.
    float cur = curx;
#pragma unroll
    for (int m = 0; m < 31; ++m) {
      if (m == 15 || m == 23) {           // k=3, s=2
        float a = __shfl(cur, 2 * lane);
        float b = __shfl(cur, 2 * lane + 1);
        float c = __shfl(cur, 2 * lane + 2);
        cur = fmaxf(fmaxf(a, b), c);
      } else {                            // k=2, s=1
        cur = fmaxf(cur, __shfl_down(cur, 1));
      }
      if (lane < S_LEN[m]) tile[lane * (S_ST[m] * 65) + S_OFF[m]] = cur;
    }

    // Prefetch next tile's input; overlaps with the emit stores below.
    const int tn = t + gridDim.x;
    float nx = 0.f;
    if (tn < ntiles) nx = (tn < nrows) ? x[(size_t)tn * 64 + lane] : 1.0f;

    // Emit: 16x (ds_read_b128 + global_store_dwordx4), fully coalesced,
    // fixed LDS addresses (no indirection -> short chains into store queue).
    float4* o4 = (float4*)(out + (size_t)t * 4096);
    const float4* t4 = (const float4*)tile;
#pragma unroll
    for (int it = 0; it < 16; ++it)
      o4[it * 64 + lane] = t4[it * 64 + lane];

    curx = nx;
  }
}

extern "C" void kernel_launch(void* const* d_in, const int* in_sizes, int n_in,
                              void* d_out, int out_size, void* d_ws, size_t ws_size,
                              hipStream_t stream) {
  const float* x = (const float*)d_in[0];        // fp32 input (32,512,64)
  float* out = (float*)d_out;                    // fp32 output

  const int nx     = in_sizes[0];                // B*D*64 = 1048576
  const int nrows  = nx / 64;                    // 16384 map tiles
  const int ntiles = out_size / 4096;            // 16448 = map + 32 mask tiles

  // 8 tiles per block: 2056 blocks, all resident (16 KB LDS -> 10 blocks/CU
  // capacity vs 8.03 needed), single scheduling round, perfectly balanced.
  const int blocks = (ntiles + 7) / 8;
  sparse_pool_kernel<<<dim3(blocks), 64, 0, stream>>>(x, out, nrows, ntiles);
}